// Round 2
// baseline (2013.962 us; speedup 1.0000x reference)
//
#include <hip/hip_runtime.h>

// VQ-VAE nearest-code lookup via MFMA filter + exact fp32 refine.
// N=65536 tokens, K=1024 codes, D=256, fp32 in/out.
// out layout (flat f32): values[N*256] | indices[N] (as float) | vectors[N*256]
//
// pass0: weight -> bf16 (RTNE) + sqr[k] (fp32)
// pass1: bf16 MFMA approx scores; per-row min m_r, per-(row, 64-code group)
//        tilemin (stored in out's values region as scratch); init cand = ~0
// pass2: exact fp32 rescore of surviving groups (tilemin <= m_r + MARGIN);
//        lexicographic (score,idx) u64 atomicMin  == np.argmin semantics
// pass3: gather weight[idx] -> values & vectors, write indices
//
// Margin proof: |approx-exact| = 2|cov_bf16 - cov_f32| <= 2*2^-8*sum|a_i b_i|
// <= ~2.3 worst case; survival needs margin >= 2*err ~ 4.6; MARGIN=12 -> 2.6x slack.

constexpr int N_TOK = 65536;
constexpr int KC    = 1024;
constexpr int D     = 256;

constexpr size_t IDX_OFF = (size_t)N_TOK * D;   // 16777216 floats
constexpr size_t VEC_OFF = IDX_OFF + N_TOK;     // 16842752 floats

#define MARGIN 12.0f

typedef __attribute__((ext_vector_type(8))) short bf16x8;
typedef __attribute__((ext_vector_type(4))) float f32x4;

__device__ inline unsigned short f2bf(float x) {
    // RTNE f32 -> bf16 (finite inputs only)
    unsigned int u = __float_as_uint(x);
    unsigned int r = (u + 0x7FFFu + ((u >> 16) & 1u)) >> 16;
    return (unsigned short)r;
}

__device__ inline unsigned int fkey(float f) {
    // order-preserving encoding of float into uint
    unsigned int b = __float_as_uint(f);
    return (b & 0x80000000u) ? ~b : (b | 0x80000000u);
}

// ---------------- pass 0: weight -> bf16, sqr ----------------
__global__ __launch_bounds__(64)
void vq_prep(const float* __restrict__ w, unsigned short* __restrict__ wbf,
             float* __restrict__ sqr) {
    const int code = blockIdx.x;
    const int lane = threadIdx.x;           // 64 lanes
    float4 v = ((const float4*)w)[(size_t)code * 64 + lane];
    float s = v.x * v.x + v.y * v.y + v.z * v.z + v.w * v.w;
#pragma unroll
    for (int off = 32; off >= 1; off >>= 1) s += __shfl_xor(s, off, 64);
    unsigned short* d = wbf + (size_t)code * D + lane * 4;
    d[0] = f2bf(v.x); d[1] = f2bf(v.y); d[2] = f2bf(v.z); d[3] = f2bf(v.w);
    if (lane == 0) sqr[code] = s;
}

// ---------------- pass 1: MFMA approx scores ----------------
// 512 blocks x 256 thr; wave handles 32 rows (2 row-tiles), all 1024 codes.
// A-frags in registers (64 VGPR); B-frags direct from L2-hot bf16 weight.
__global__ __launch_bounds__(256)
void vq_pass1(const float* __restrict__ input, const unsigned short* __restrict__ wbf,
              const float* __restrict__ sqr, float* __restrict__ tilemin,
              float* __restrict__ m_r, unsigned long long* __restrict__ cand) {
    const int wave = threadIdx.x >> 6;
    const int lane = threadIdx.x & 63;
    const int col  = lane & 15;             // A m-index / B n-index / C col
    const int quad = lane >> 4;             // k-octet select; C row = quad*4+reg
    const int row_base = blockIdx.x * 128 + wave * 32;

    // load + convert A fragments: 2 row-tiles x 8 k-tiles, 8 bf16 each
    bf16x8 a[2][8];
#pragma unroll
    for (int rt = 0; rt < 2; ++rt) {
        const float* ar = input + (size_t)(row_base + rt * 16 + col) * D;
#pragma unroll
        for (int kt = 0; kt < 8; ++kt) {
            const int k0 = kt * 32 + quad * 8;
            float4 f0 = *(const float4*)(ar + k0);
            float4 f1 = *(const float4*)(ar + k0 + 4);
            bf16x8 v;
            v[0] = (short)f2bf(f0.x); v[1] = (short)f2bf(f0.y);
            v[2] = (short)f2bf(f0.z); v[3] = (short)f2bf(f0.w);
            v[4] = (short)f2bf(f1.x); v[5] = (short)f2bf(f1.y);
            v[6] = (short)f2bf(f1.z); v[7] = (short)f2bf(f1.w);
            a[rt][kt] = v;
        }
    }

    float rmin[2][4];
#pragma unroll
    for (int rt = 0; rt < 2; ++rt)
#pragma unroll
        for (int rg = 0; rg < 4; ++rg) rmin[rt][rg] = 3.4e38f;

    for (int g = 0; g < 16; ++g) {          // 16 groups of 64 codes
        float gmin[2][4];
#pragma unroll
        for (int rt = 0; rt < 2; ++rt)
#pragma unroll
            for (int rg = 0; rg < 4; ++rg) gmin[rt][rg] = 3.4e38f;

#pragma unroll
        for (int t = 0; t < 4; ++t) {       // 4 tiles of 16 codes
            const int c0 = g * 64 + t * 16;
            const unsigned short* wr = wbf + (size_t)(c0 + col) * D + quad * 8;
            bf16x8 b[8];
#pragma unroll
            for (int kt = 0; kt < 8; ++kt)
                b[kt] = *(const bf16x8*)(wr + kt * 32);
            const float sq = sqr[c0 + col];
#pragma unroll
            for (int rt = 0; rt < 2; ++rt) {
                f32x4 acc = {0.f, 0.f, 0.f, 0.f};
#pragma unroll
                for (int kt = 0; kt < 8; ++kt)
                    acc = __builtin_amdgcn_mfma_f32_16x16x32_bf16(a[rt][kt], b[kt], acc, 0, 0, 0);
#pragma unroll
                for (int rg = 0; rg < 4; ++rg) {
                    float s = sq - 2.0f * acc[rg];   // score(row=quad*4+rg, code=c0+col)
                    gmin[rt][rg] = fminf(gmin[rt][rg], s);
                }
            }
        }
        // reduce min over the 16 col-lanes (xor 1,2,4,8 preserves quad)
#pragma unroll
        for (int off = 1; off <= 8; off <<= 1)
#pragma unroll
            for (int rt = 0; rt < 2; ++rt)
#pragma unroll
                for (int rg = 0; rg < 4; ++rg)
                    gmin[rt][rg] = fminf(gmin[rt][rg], __shfl_xor(gmin[rt][rg], off, 64));

        if (col == 0) {
#pragma unroll
            for (int rt = 0; rt < 2; ++rt)
#pragma unroll
                for (int rg = 0; rg < 4; ++rg) {
                    int row = row_base + rt * 16 + quad * 4 + rg;
                    tilemin[(size_t)row * 16 + g] = gmin[rt][rg];
                }
        }
#pragma unroll
        for (int rt = 0; rt < 2; ++rt)
#pragma unroll
            for (int rg = 0; rg < 4; ++rg)
                rmin[rt][rg] = fminf(rmin[rt][rg], gmin[rt][rg]);
    }

    if (col == 0) {
#pragma unroll
        for (int rt = 0; rt < 2; ++rt)
#pragma unroll
            for (int rg = 0; rg < 4; ++rg) {
                int row = row_base + rt * 16 + quad * 4 + rg;
                m_r[row] = rmin[rt][rg];
            }
    }
    if (lane < 32) cand[row_base + lane] = 0xFFFFFFFFFFFFFFFFULL;
}

// ---------------- pass 2: exact refine of surviving groups ----------------
__global__ __launch_bounds__(256)
void vq_pass2(const float* __restrict__ input, const float* __restrict__ weight,
              const float* __restrict__ sqr, const float* __restrict__ tilemin,
              const float* __restrict__ m_r, unsigned long long* __restrict__ cand) {
    __shared__ int cnt;
    __shared__ unsigned short list[1024];   // max 64 rows * 16 groups
    const int tid  = threadIdx.x;
    const int row0 = blockIdx.x * 64;

    if (tid == 0) cnt = 0;
    __syncthreads();
    if (tid < 64) {
        const float th = m_r[row0 + tid] + MARGIN;
        for (int g = 0; g < 16; ++g) {
            if (tilemin[(size_t)(row0 + tid) * 16 + g] <= th) {
                int p = atomicAdd(&cnt, 1);
                list[p] = (unsigned short)((tid << 4) | g);
            }
        }
    }
    __syncthreads();

    const int wave = tid >> 6, lane = tid & 63;
    const int n = cnt;
    const float4* in4 = (const float4*)input;
    const float4* w4  = (const float4*)weight;

    for (int e = wave; e < n; e += 4) {
        const int ent  = list[e];
        const int row  = row0 + (ent >> 4);
        const int code = (ent & 15) * 64 + lane;
        const float4* zr = in4 + (size_t)row * 64;    // wave-uniform (broadcast)
        const float4* wr = w4 + (size_t)code * 64;
        float d0 = 0.f, d1 = 0.f, d2 = 0.f, d3 = 0.f;
#pragma unroll 4
        for (int i = 0; i < 64; i += 4) {
            float4 a0 = zr[i],     b0 = wr[i];
            float4 a1 = zr[i + 1], b1 = wr[i + 1];
            float4 a2 = zr[i + 2], b2 = wr[i + 2];
            float4 a3 = zr[i + 3], b3 = wr[i + 3];
            d0 = fmaf(a0.x, b0.x, d0); d0 = fmaf(a0.y, b0.y, d0);
            d0 = fmaf(a0.z, b0.z, d0); d0 = fmaf(a0.w, b0.w, d0);
            d1 = fmaf(a1.x, b1.x, d1); d1 = fmaf(a1.y, b1.y, d1);
            d1 = fmaf(a1.z, b1.z, d1); d1 = fmaf(a1.w, b1.w, d1);
            d2 = fmaf(a2.x, b2.x, d2); d2 = fmaf(a2.y, b2.y, d2);
            d2 = fmaf(a2.z, b2.z, d2); d2 = fmaf(a2.w, b2.w, d2);
            d3 = fmaf(a3.x, b3.x, d3); d3 = fmaf(a3.y, b3.y, d3);
            d3 = fmaf(a3.z, b3.z, d3); d3 = fmaf(a3.w, b3.w, d3);
        }
        const float dot = (d0 + d1) + (d2 + d3);
        const float s = sqr[code] - 2.0f * dot;
        unsigned long long key =
            ((unsigned long long)fkey(s) << 32) | (unsigned int)code;
#pragma unroll
        for (int off = 32; off >= 1; off >>= 1) {
            unsigned long long o = __shfl_xor(key, off, 64);
            key = (o < key) ? o : key;
        }
        if (lane == 0) atomicMin(&cand[row], key);
    }
}

// ---------------- pass 3: gather + write outputs ----------------
__global__ __launch_bounds__(256)
void vq_pass3(const float* __restrict__ weight,
              const unsigned long long* __restrict__ cand,
              float* __restrict__ out) {
    __shared__ int fin[64];
    const int tid  = threadIdx.x;
    const int row0 = blockIdx.x * 64;
    if (tid < 64) {
        int idx = (int)(unsigned int)(cand[row0 + tid] & 0xFFFFFFFFULL);
        fin[tid] = idx;
        out[IDX_OFF + row0 + tid] = (float)idx;
    }
    __syncthreads();
    const float4* w4 = (const float4*)weight;
    float4* out4 = (float4*)out;
#pragma unroll
    for (int k = 0; k < 16; ++k) {
        int i = tid + k * 256;
        int r = i >> 6, q = i & 63;
        float4 v = w4[(size_t)fin[r] * 64 + q];
        size_t o = (size_t)(row0 + r) * 64 + q;
        out4[o] = v;                    // values
        out4[VEC_OFF / 4 + o] = v;      // vectors
    }
}

extern "C" void kernel_launch(void* const* d_in, const int* in_sizes, int n_in,
                              void* d_out, int out_size, void* d_ws, size_t ws_size,
                              hipStream_t stream) {
    const float* input  = (const float*)d_in[0];   // [64,32,32,256] f32
    const float* weight = (const float*)d_in[1];   // [1024,256] f32
    float* out = (float*)d_out;

    // ws layout (1.29 MB total)
    unsigned short* wbf = (unsigned short*)d_ws;                          // 512 KB
    float* sqr = (float*)((char*)d_ws + 524288);                          // 4 KB
    float* m_r = (float*)((char*)d_ws + 528384);                          // 256 KB
    unsigned long long* cand = (unsigned long long*)((char*)d_ws + 794624); // 512 KB

    // tilemin scratch lives in out's values region (4 MB); pass3 overwrites it
    float* tilemin = out;

    vq_prep <<<KC, 64, 0, stream>>>(weight, wbf, sqr);
    vq_pass1<<<N_TOK / 128, 256, 0, stream>>>(input, wbf, sqr, tilemin, m_r, cand);
    vq_pass2<<<N_TOK / 64, 256, 0, stream>>>(input, weight, sqr, tilemin, m_r, cand);
    vq_pass3<<<N_TOK / 64, 256, 0, stream>>>(weight, cand, out);
}